// Round 9
// baseline (555.194 us; speedup 1.0000x reference)
//
#include <hip/hip_runtime.h>

// OnceAggregation R9: R8 + register-footprint cut for 3 waves/SIMD occupancy.
//  - y1/y2 kept as packed bf16 pairs (cvt_pk) with exact-f32 LN stats accumulated
//    on the fly; normalize at unpack time. Halves accumulator registers.
//  - walk tile split into 2 passes of 128 channels (8KB/wave LDS, 32KB/block)
//    so 3 blocks/CU fit; __launch_bounds__(256,3).
//  - sidx+vsort merged into int2 pv[].
// Pipeline: memset ; pack_hist ; scan ; scatter(pv) ;
//   point_fused (gather -> L1 -> L2 -> out_pts GEMM -> 2x[LDS stage+walk] -> agg) ;
//   vox_fused. Segment semantics identical to R8 (passed).

typedef __attribute__((ext_vector_type(2))) float f32x2;
typedef __attribute__((ext_vector_type(4))) float f32x4;
typedef __attribute__((ext_vector_type(8))) short s16x8;
typedef __attribute__((ext_vector_type(4))) unsigned int u32x4;

static constexpr int NP = 500000;   // 32 | NP
static constexpr int NV = 60000;

__device__ __forceinline__ unsigned short f2bf(float f){
  unsigned int u = __float_as_uint(f);
  u = (u + 0x7FFFu + ((u >> 16) & 1u)) >> 16;   // RNE
  return (unsigned short)u;
}

__device__ __forceinline__ unsigned int cvtpk(float lo, float hi){
  unsigned int r;
  asm("v_cvt_pk_bf16_f32 %0, %1, %2" : "=v"(r) : "v"(lo), "v"(hi));
  return r;
}

__device__ __forceinline__ unsigned int pkmaxu16(unsigned int a, unsigned int b){
  unsigned int r;
  asm("v_pk_max_u16 %0, %1, %2" : "=v"(r) : "v"(a), "v"(b));
  return r;
}

// ---------------- pack weights + out_coors + histogram ----------------
__device__ __forceinline__ void pack_one(const float* __restrict__ w,
                                         unsigned short* __restrict__ dst,
                                         int K, int C, bool perm, int idx){
  int j = idx & 7, l = (idx >> 3) & 63, rest = idx >> 9;
  int kcn = K >> 5;
  int kc = rest % kcn, n = rest / kcn;
  int g = l >> 4, t = l & 15;
  int k = perm ? (kc * 32 + ((j >> 2) << 4) + g * 4 + (j & 3))
               : (kc * 32 + g * 8 + j);
  dst[idx] = f2bf(w[(size_t)k * C + n * 16 + t]);
}

__global__ void pack_hist_kernel(const float* __restrict__ w1, const float* __restrict__ w2,
                                 const float* __restrict__ ow, const float* __restrict__ pw1,
                                 const float* __restrict__ pw2,
                                 unsigned short* __restrict__ w1p, unsigned short* __restrict__ w2p,
                                 unsigned short* __restrict__ owp, unsigned short* __restrict__ pw1p,
                                 unsigned short* __restrict__ pw2p,
                                 float* __restrict__ out_coors,
                                 const int* __restrict__ coors, int* __restrict__ counts){
  int stride = gridDim.x * blockDim.x;
  const int T = 196608 + NV + NP;
  for (int i = blockIdx.x * blockDim.x + threadIdx.x; i < T; i += stride){
    if      (i < 16384)       pack_one(w1,  w1p,  128, 128, false, i);
    else if (i < 49152)       pack_one(w2,  w2p,  128, 256, true,  i - 16384);
    else if (i < 65536)       pack_one(ow,  owp,  256, 64,  true,  i - 49152);
    else if (i < 131072)      pack_one(pw1, pw1p, 256, 256, true,  i - 65536);
    else if (i < 196608)      pack_one(pw2, pw2p, 256, 256, true,  i - 131072);
    else if (i < 196608 + NV) out_coors[i - 196608] = (float)(i - 196608);
    else                      atomicAdd(&counts[coors[i - 196608 - NV]], 1);
  }
}

// ---------------- counting sort: coalesced scan + scatter ----------------
__global__ __launch_bounds__(1024)
void scan_kernel(const int* __restrict__ counts, int* __restrict__ cursor){
  __shared__ int part[1024];
  const int t = threadIdx.x;
  constexpr int PER = (NV + 1023) / 1024;   // 59
  int s = 0;
  for (int i = 0; i < PER; ++i){ int v = i * 1024 + t; if (v < NV) s += counts[v]; }
  part[t] = s;
  __syncthreads();
  for (int d = 1; d < 1024; d <<= 1){
    int u = (t >= d) ? part[t - d] : 0;
    __syncthreads();
    part[t] += u;
    __syncthreads();
  }
  int run = (t > 0) ? part[t - 1] : 0;
  for (int i = 0; i < PER; ++i){
    int v = i * 1024 + t;
    if (v < NV){ cursor[v] = run; run += counts[v]; }
  }
}

__global__ void scatter_kernel(const int* __restrict__ coors, int* __restrict__ cursor,
                               int2* __restrict__ pv){
  int stride = gridDim.x * blockDim.x;
  for (int i = blockIdx.x * blockDim.x + threadIdx.x; i < NP; i += stride){
    int v = coors[i];
    int p = atomicAdd(&cursor[v], 1);
    pv[p] = make_int2(i, v);
  }
}

// gathered x-row fragments: lane (g) holds cols q*8..q*8+7, q = kc*4+g
__device__ __forceinline__ void load_x(const float* __restrict__ feats,
                                       const float* __restrict__ fclus,
                                       int orig, int g, s16x8* bf){
  const float* rp = feats + (size_t)orig * 125;
#pragma unroll
  for (int kc = 0; kc < 4; ++kc){
    f32x4 u0, u1;
    if (kc < 3 || g < 3){
      int q = kc * 4 + g;
      u0 = *(const f32x4*)(rp + q * 8);
      u1 = *(const f32x4*)(rp + q * 8 + 4);
    } else {
      const float* fc = fclus + (size_t)orig * 3;
      u0 = *(const f32x4*)(rp + 120);
      u1[0] = rp[124];
      u1[1] = fc[0] * 0.05f; u1[2] = fc[1] * 0.05f; u1[3] = fc[2] * 0.25f;
    }
    u32x4 t;
    t[0] = cvtpk(u0[0], u0[1]); t[1] = cvtpk(u0[2], u0[3]);
    t[2] = cvtpk(u1[0], u1[1]); t[3] = cvtpk(u1[2], u1[3]);
    bf[kc] = __builtin_bit_cast(s16x8, t);
  }
}

// Fused GEMM layer with packed-bf16 accumulator:
//   p[2n], p[2n+1] <- cvtpk(post-bias y) ; exact f32 stats into s,q.
template<int KC, int NT>
__device__ __forceinline__ void gemm_pack(const unsigned int* pa_in, const unsigned int* pb_in,
                                          const unsigned short* __restrict__ Wp,
                                          const float* __restrict__ bias,
                                          int lane, int g,
                                          unsigned int* pa, unsigned int* pb,
                                          float& sA, float& qA, float& sB, float& qB){
#pragma unroll
  for (int n = 0; n < NT; ++n){
    f32x4 aA = {0.f,0.f,0.f,0.f}, aB = {0.f,0.f,0.f,0.f};
#pragma unroll
    for (int kc = 0; kc < KC; ++kc){
      s16x8 w = *(const s16x8*)(Wp + ((n * KC + kc) * 64 + lane) * 8);
      s16x8 fa = __builtin_bit_cast(s16x8, *(const u32x4*)&pa_in[4 * kc]);
      s16x8 fb = __builtin_bit_cast(s16x8, *(const u32x4*)&pb_in[4 * kc]);
      aA = __builtin_amdgcn_mfma_f32_16x16x32_bf16(w, fa, aA, 0, 0, 0);
      aB = __builtin_amdgcn_mfma_f32_16x16x32_bf16(w, fb, aB, 0, 0, 0);
    }
    f32x4 bv = *(const f32x4*)(bias + n * 16 + g * 4);
#pragma unroll
    for (int i = 0; i < 4; ++i){
      aA[i] += bv[i]; sA += aA[i]; qA += aA[i] * aA[i];
      aB[i] += bv[i]; sB += aB[i]; qB += aB[i] * aB[i];
    }
    pa[2*n] = cvtpk(aA[0], aA[1]); pa[2*n+1] = cvtpk(aA[2], aA[3]);
    pb[2*n] = cvtpk(aB[0], aB[1]); pb[2*n+1] = cvtpk(aB[2], aB[3]);
  }
}

// LN finalize on packed pairs: reduce stats across g-groups, normalize in place.
template<int NT, int C>
__device__ __forceinline__ void ln_pack(unsigned int* pa, unsigned int* pb,
                                        const float* __restrict__ gam,
                                        const float* __restrict__ bet, int g,
                                        float sA, float qA, float sB, float qB){
  sA += __shfl_xor(sA, 16); sA += __shfl_xor(sA, 32);
  qA += __shfl_xor(qA, 16); qA += __shfl_xor(qA, 32);
  sB += __shfl_xor(sB, 16); sB += __shfl_xor(sB, 32);
  qB += __shfl_xor(qB, 16); qB += __shfl_xor(qB, 32);
  float mA = sA * (1.f / C), mB = sB * (1.f / C);
  float rA = rsqrtf(qA * (1.f / C) - mA * mA + 1e-3f);
  float rB = rsqrtf(qB * (1.f / C) - mB * mB + 1e-3f);
#pragma unroll
  for (int n = 0; n < NT; ++n){
    f32x4 gv  = *(const f32x4*)(gam + n * 16 + g * 4);
    f32x4 bev = *(const f32x4*)(bet + n * 16 + g * 4);
#pragma unroll
    for (int h = 0; h < 2; ++h){
      unsigned int ua = pa[2*n+h], ub = pb[2*n+h];
      float a0 = __uint_as_float(ua << 16), a1 = __uint_as_float(ua & 0xffff0000u);
      float b0 = __uint_as_float(ub << 16), b1 = __uint_as_float(ub & 0xffff0000u);
      a0 = fmaxf((a0 - mA) * rA * gv[2*h]   + bev[2*h],   0.f);
      a1 = fmaxf((a1 - mA) * rA * gv[2*h+1] + bev[2*h+1], 0.f);
      b0 = fmaxf((b0 - mB) * rB * gv[2*h]   + bev[2*h],   0.f);
      b1 = fmaxf((b1 - mB) * rB * gv[2*h+1] + bev[2*h+1], 0.f);
      pa[2*n+h] = cvtpk(a0, a1);
      pb[2*n+h] = cvtpk(b0, b1);
    }
  }
}

// flush lane's 2 channels of run max for voxel v (channel base c0).
__device__ __forceinline__ void flush2(float* __restrict__ agg, int v, int c0,
                                       unsigned int q, bool partial){
  float* base = agg + (size_t)v * 256 + c0;
  unsigned int a0 = q << 16, a1 = q & 0xffff0000u;
  if (!partial){
    f32x2 o; o[0] = __uint_as_float(a0); o[1] = __uint_as_float(a1);
    *(f32x2*)base = o;
  } else {
    unsigned int* ab = (unsigned int*)base;
    atomicMax(ab + 0, a0); atomicMax(ab + 1, a1);
  }
}

// ---------------- fused point pipeline + per-wave 2-pass tile segment-max ----------------
__global__ __launch_bounds__(256, 3)
void point_fused_kernel(const float* __restrict__ feats, const float* __restrict__ fclus,
                        const int2* __restrict__ pv,
                        const unsigned short* __restrict__ w1p,
                        const unsigned short* __restrict__ w2p,
                        const unsigned short* __restrict__ owp,
                        const float* __restrict__ b1, const float* __restrict__ g1,
                        const float* __restrict__ be1,
                        const float* __restrict__ b2, const float* __restrict__ g2,
                        const float* __restrict__ be2,
                        const float* __restrict__ ob, const float* __restrict__ og,
                        const float* __restrict__ obe,
                        float* __restrict__ agg,
                        float* __restrict__ out_pts){
  __shared__ __align__(16) unsigned short tile[4][32 * 128];   // 8 KB per wave
  const int lane = threadIdx.x & 63;
  const int wave = threadIdx.x >> 6;
  const int g = lane >> 4, t = lane & 15;
  const int m0 = blockIdx.x * 128 + wave * 32;   // 32 | NP -> whole waves only
  if (m0 >= NP) return;
  const int2 pA = pv[m0 + t];
  const int2 pB = pv[m0 + 16 + t];
  const int origA = pA.x, origB = pB.x;
  const int myv = pv[m0 + (lane & 31)].y;        // wave's 32 voxel ids in lane order

  // layer1 inputs
  s16x8 bfA[4], bfB[4];
  load_x(feats, fclus, origA, g, bfA);
  load_x(feats, fclus, origB, g, bfB);

  // layer1: packed y1 (16 u32 per stream)
  unsigned int p1a[16], p1b[16];
  {
    float sA = 0, qA = 0, sB = 0, qB = 0;
    gemm_pack<4, 8>((const unsigned int*)bfA, (const unsigned int*)bfB, w1p, b1,
                    lane, g, p1a, p1b, sA, qA, sB, qB);
    ln_pack<8, 128>(p1a, p1b, g1, be1, g, sA, qA, sB, qB);
  }

  // layer2: packed y2 (32 u32 per stream) == f3 fragments
  unsigned int p2a[32], p2b[32];
  {
    float sA = 0, qA = 0, sB = 0, qB = 0;
    gemm_pack<4, 16>(p1a, p1b, w2p, b2, lane, g, p2a, p2b, sA, qA, sB, qB);
    ln_pack<16, 256>(p2a, p2b, g2, be2, g, sA, qA, sB, qB);
  }

  // out layer (reads p2 as fragments) -> scatter to original point order
  {
    f32x4 d3a[4], d3b[4];
#pragma unroll
    for (int n = 0; n < 4; ++n){
      f32x4 aA = {0.f,0.f,0.f,0.f}, aB = {0.f,0.f,0.f,0.f};
#pragma unroll
      for (int kc = 0; kc < 8; ++kc){
        s16x8 w = *(const s16x8*)(owp + ((n * 8 + kc) * 64 + lane) * 8);
        s16x8 fa = __builtin_bit_cast(s16x8, *(const u32x4*)&p2a[4 * kc]);
        s16x8 fb = __builtin_bit_cast(s16x8, *(const u32x4*)&p2b[4 * kc]);
        aA = __builtin_amdgcn_mfma_f32_16x16x32_bf16(w, fa, aA, 0, 0, 0);
        aB = __builtin_amdgcn_mfma_f32_16x16x32_bf16(w, fb, aB, 0, 0, 0);
      }
      d3a[n] = aA; d3b[n] = aB;
    }
    // bias+LN+relu (f32 path, small)
    float sA = 0, qA = 0, sB = 0, qB = 0;
#pragma unroll
    for (int n = 0; n < 4; ++n){
      f32x4 bv = *(const f32x4*)(ob + n * 16 + g * 4);
#pragma unroll
      for (int i = 0; i < 4; ++i){
        d3a[n][i] += bv[i]; sA += d3a[n][i]; qA += d3a[n][i] * d3a[n][i];
        d3b[n][i] += bv[i]; sB += d3b[n][i]; qB += d3b[n][i] * d3b[n][i];
      }
    }
    sA += __shfl_xor(sA, 16); sA += __shfl_xor(sA, 32);
    qA += __shfl_xor(qA, 16); qA += __shfl_xor(qA, 32);
    sB += __shfl_xor(sB, 16); sB += __shfl_xor(sB, 32);
    qB += __shfl_xor(qB, 16); qB += __shfl_xor(qB, 32);
    float mA = sA * (1.f/64), mB = sB * (1.f/64);
    float rA = rsqrtf(qA * (1.f/64) - mA * mA + 1e-3f);
    float rB = rsqrtf(qB * (1.f/64) - mB * mB + 1e-3f);
#pragma unroll
    for (int n = 0; n < 4; ++n){
      f32x4 gv  = *(const f32x4*)(og  + n * 16 + g * 4);
      f32x4 bev = *(const f32x4*)(obe + n * 16 + g * 4);
      f32x4 oA, oB;
#pragma unroll
      for (int i = 0; i < 4; ++i){
        oA[i] = fmaxf((d3a[n][i] - mA) * rA * gv[i] + bev[i], 0.f);
        oB[i] = fmaxf((d3b[n][i] - mB) * rB * gv[i] + bev[i], 0.f);
      }
      *(f32x4*)(out_pts + (size_t)origA * 64 + n * 16 + g * 4) = oA;
      *(f32x4*)(out_pts + (size_t)origB * 64 + n * 16 + g * 4) = oB;
    }
  }

  // ---- 2-pass per-wave tile + wave-uniform run walk ----
  unsigned short* my = tile[wave];
  const int vleft  = (m0 > 0) ? pv[m0 - 1].y : -1;
  const int vright = (m0 + 32 < NP) ? pv[m0 + 32].y : -1;
  const int rA = t, rB = t + 16;
  const int slot = lane >> 2;              // 16B slot holding lane's 2 channels
  const int off  = (lane & 3) * 2;         // u16 offset within slot

#pragma unroll
  for (int pass = 0; pass < 2; ++pass){
    // stage 32 rows x 128 channels (kc' = 0..3 of this pass), swizzled slots
#pragma unroll
    for (int kcp = 0; kcp < 4; ++kcp){
      int s = kcp * 4 + g;
      int spA = (s & ~7) | ((s & 7) ^ (rA & 7));
      int spB = (s & ~7) | ((s & 7) ^ (rB & 7));
      int kc = pass * 4 + kcp;
      *(s16x8*)&my[rA * 128 + spA * 8] = __builtin_bit_cast(s16x8, *(const u32x4*)&p2a[4 * kc]);
      *(s16x8*)&my[rB * 128 + spB * 8] = __builtin_bit_cast(s16x8, *(const u32x4*)&p2b[4 * kc]);
    }
    // walk: lane owns channels pass*128 + lane*2 .. +1
    const int c0 = pass * 128 + lane * 2;
    unsigned int q = 0;
    int cur = __shfl(myv, 0);
    int rs = 0;
#pragma unroll
    for (int r = 0; r < 32; ++r){
      int v = __shfl(myv, r);
      if (v != cur){
        flush2(agg, cur, c0, q, rs == 0 && cur == vleft);
        q = 0; cur = v; rs = r;
      }
      int sp = (slot & ~7) | ((slot & 7) ^ (r & 7));
      q = pkmaxu16(q, *(const unsigned int*)&my[r * 128 + sp * 8 + off]);
    }
    flush2(agg, cur, c0, q, (rs == 0 && cur == vleft) || cur == vright);
  }
}

// ---------------- fused voxel pipeline (agg f32 -> pl1 -> pl2) ----------------
__global__ __launch_bounds__(256, 2)
void vox_fused_kernel(const float* __restrict__ agg,
                      const unsigned short* __restrict__ pw1p,
                      const unsigned short* __restrict__ pw2p,
                      const float* __restrict__ pb1, const float* __restrict__ pg1,
                      const float* __restrict__ pbe1,
                      const float* __restrict__ pb2, const float* __restrict__ pg2,
                      const float* __restrict__ pbe2,
                      float* __restrict__ out_vox){
  const int lane = threadIdx.x & 63;
  const int wave = threadIdx.x >> 6;
  const int m0 = blockIdx.x * 128 + wave * 32;
  if (m0 >= NV) return;
  const int g = lane >> 4, t = lane & 15;
  const size_t mA = m0 + t, mB = m0 + 16 + t;

  unsigned int ba[32], bb[32];
#pragma unroll
  for (int kc = 0; kc < 8; ++kc){
    const float* pa = agg + mA * 256 + kc * 32 + g * 8;
    const float* pb = agg + mB * 256 + kc * 32 + g * 8;
    f32x4 a0 = *(const f32x4*)pa, a1 = *(const f32x4*)(pa + 4);
    f32x4 b0 = *(const f32x4*)pb, b1v = *(const f32x4*)(pb + 4);
    ba[4*kc]   = cvtpk(a0[0], a0[1]); ba[4*kc+1] = cvtpk(a0[2], a0[3]);
    ba[4*kc+2] = cvtpk(a1[0], a1[1]); ba[4*kc+3] = cvtpk(a1[2], a1[3]);
    bb[4*kc]   = cvtpk(b0[0], b0[1]); bb[4*kc+1] = cvtpk(b0[2], b0[3]);
    bb[4*kc+2] = cvtpk(b1v[0], b1v[1]); bb[4*kc+3] = cvtpk(b1v[2], b1v[3]);
  }

  unsigned int pa1[32], pb1a[32];
  {
    float sA = 0, qA = 0, sB = 0, qB = 0;
    gemm_pack<8, 16>(ba, bb, pw1p, pb1, lane, g, pa1, pb1a, sA, qA, sB, qB);
    ln_pack<16, 256>(pa1, pb1a, pg1, pbe1, g, sA, qA, sB, qB);
  }

  // pl2: f32 output path
  f32x4 da[16], db[16];
#pragma unroll
  for (int n = 0; n < 16; ++n){
    f32x4 aA = {0.f,0.f,0.f,0.f}, aB = {0.f,0.f,0.f,0.f};
#pragma unroll
    for (int kc = 0; kc < 8; ++kc){
      s16x8 w = *(const s16x8*)(pw2p + ((n * 8 + kc) * 64 + lane) * 8);
      s16x8 fa = __builtin_bit_cast(s16x8, *(const u32x4*)&pa1[4 * kc]);
      s16x8 fb = __builtin_bit_cast(s16x8, *(const u32x4*)&pb1a[4 * kc]);
      aA = __builtin_amdgcn_mfma_f32_16x16x32_bf16(w, fa, aA, 0, 0, 0);
      aB = __builtin_amdgcn_mfma_f32_16x16x32_bf16(w, fb, aB, 0, 0, 0);
    }
    da[n] = aA; db[n] = aB;
  }
  float sA = 0, qA = 0, sB = 0, qB = 0;
#pragma unroll
  for (int n = 0; n < 16; ++n){
    f32x4 bv = *(const f32x4*)(pb2 + n * 16 + g * 4);
#pragma unroll
    for (int i = 0; i < 4; ++i){
      da[n][i] += bv[i]; sA += da[n][i]; qA += da[n][i] * da[n][i];
      db[n][i] += bv[i]; sB += db[n][i]; qB += db[n][i] * db[n][i];
    }
  }
  sA += __shfl_xor(sA, 16); sA += __shfl_xor(sA, 32);
  qA += __shfl_xor(qA, 16); qA += __shfl_xor(qA, 32);
  sB += __shfl_xor(sB, 16); sB += __shfl_xor(sB, 32);
  qB += __shfl_xor(qB, 16); qB += __shfl_xor(qB, 32);
  float mAs = sA * (1.f/256), mBs = sB * (1.f/256);
  float rAs = rsqrtf(qA * (1.f/256) - mAs * mAs + 1e-3f);
  float rBs = rsqrtf(qB * (1.f/256) - mBs * mBs + 1e-3f);
#pragma unroll
  for (int n = 0; n < 16; ++n){
    f32x4 gv  = *(const f32x4*)(pg2  + n * 16 + g * 4);
    f32x4 bev = *(const f32x4*)(pbe2 + n * 16 + g * 4);
    f32x4 oA, oB;
#pragma unroll
    for (int i = 0; i < 4; ++i){
      oA[i] = fmaxf((da[n][i] - mAs) * rAs * gv[i] + bev[i], 0.f);
      oB[i] = fmaxf((db[n][i] - mBs) * rBs * gv[i] + bev[i], 0.f);
    }
    *(f32x4*)(out_vox + mA * 256 + n * 16 + g * 4) = oA;
    *(f32x4*)(out_vox + mB * 256 + n * 16 + g * 4) = oB;
  }
}

extern "C" void kernel_launch(void* const* d_in, const int* in_sizes, int n_in,
                              void* d_out, int out_size, void* d_ws, size_t ws_size,
                              hipStream_t stream){
  const float* features  = (const float*)d_in[1];
  const int*   coors     = (const int*)  d_in[2];
  const float* f_cluster = (const float*)d_in[3];
  const float* w1  = (const float*)d_in[4];
  const float* b1  = (const float*)d_in[5];
  const float* g1  = (const float*)d_in[6];
  const float* be1 = (const float*)d_in[7];
  const float* w2  = (const float*)d_in[8];
  const float* b2  = (const float*)d_in[9];
  const float* g2  = (const float*)d_in[10];
  const float* be2 = (const float*)d_in[11];
  const float* pw1 = (const float*)d_in[12];
  const float* pb1 = (const float*)d_in[13];
  const float* pg1 = (const float*)d_in[14];
  const float* pbe1= (const float*)d_in[15];
  const float* pw2 = (const float*)d_in[16];
  const float* pb2 = (const float*)d_in[17];
  const float* pg2 = (const float*)d_in[18];
  const float* pbe2= (const float*)d_in[19];
  const float* ow  = (const float*)d_in[20];
  const float* ob  = (const float*)d_in[21];
  const float* og  = (const float*)d_in[22];
  const float* obe = (const float*)d_in[23];

  char* ws = (char*)d_ws;
  float* aggf   = (float*)(ws + 0);                          // 61,440,000 B
  int* counts   = (int*)(ws + 61500000ull);
  int* cursor   = (int*)(ws + 61800000ull);
  int2* pv      = (int2*)(ws + 62100000ull);                 // 4,000,000 B
  unsigned short* w1p = (unsigned short*)(ws + 66300000ull);
  unsigned short* w2p = (unsigned short*)(ws + 66300000ull + 1*262144ull);
  unsigned short* owp = (unsigned short*)(ws + 66300000ull + 2*262144ull);
  unsigned short* pw1p= (unsigned short*)(ws + 66300000ull + 3*262144ull);
  unsigned short* pw2p= (unsigned short*)(ws + 66300000ull + 4*262144ull);

  float* outp      = (float*)d_out;
  float* out_pts   = outp;                       // [N,64]
  float* out_vox   = outp + 32000000;            // [V,256]
  float* out_coors = outp + 47360000;            // [V] as float

  hipMemsetAsync(counts, 0, (size_t)NV * sizeof(int), stream);
  hipMemsetAsync(aggf,   0, (size_t)NV * 256 * sizeof(float), stream);

  pack_hist_kernel<<<2048, 256, 0, stream>>>(w1, w2, ow, pw1, pw2,
                                             w1p, w2p, owp, pw1p, pw2p,
                                             out_coors, coors, counts);

  scan_kernel<<<1, 1024, 0, stream>>>(counts, cursor);
  scatter_kernel<<<2048, 256, 0, stream>>>(coors, cursor, pv);

  point_fused_kernel<<<(NP + 127) / 128, 256, 0, stream>>>(
      features, f_cluster, pv, w1p, w2p, owp,
      b1, g1, be1, b2, g2, be2, ob, og, obe, aggf, out_pts);

  vox_fused_kernel<<<(NV + 127) / 128, 256, 0, stream>>>(
      aggf, pw1p, pw2p, pb1, pg1, pbe1, pb2, pg2, pbe2, out_vox);
}